// Round 11
// baseline (66.790 us; speedup 1.0000x reference)
//
#include <hip/hip_runtime.h>
#include <math.h>

#define NUM_EXPERTS 64
#define TOP_K 6
#define HIDDEN 2048
#define INTER 1024

// ---------------- Kernel 1: routing — gate GEMV + top-6 in ONE block ----------------
__global__ __launch_bounds__(1024) void k_route(const float* __restrict__ gw,
                                                const float* __restrict__ x,
                                                const float* __restrict__ bias,
                                                int* __restrict__ idx,
                                                float* __restrict__ wgt) {
    __shared__ float4 xs[HIDDEN / 4];          // 8 KB
    __shared__ float  lg[NUM_EXPERTS];
    const int t = threadIdx.x;
    const int wave = t >> 6;
    const int lane = t & 63;

    const float4* x4 = (const float4*)x;
    if (t < HIDDEN / 4) xs[t] = x4[t];
    __syncthreads();

    float s[4] = {0.f, 0.f, 0.f, 0.f};
    #pragma unroll
    for (int q = 0; q < 4; q++) {
        const int e = wave * 4 + q;
        const float4* r4 = (const float4*)(gw + (size_t)e * HIDDEN);
        #pragma unroll
        for (int j = 0; j < 8; j++) {
            float4 a = r4[lane + 64 * j];
            float4 xv = xs[lane + 64 * j];
            s[q] += a.x * xv.x + a.y * xv.y + a.z * xv.z + a.w * xv.w;
        }
    }
    #pragma unroll
    for (int o = 32; o; o >>= 1) {
        #pragma unroll
        for (int q = 0; q < 4; q++) s[q] += __shfl_down(s[q], o, 64);
    }
    if (lane == 0) {
        #pragma unroll
        for (int q = 0; q < 4; q++) lg[wave * 4 + q] = s[q];
    }
    __syncthreads();

    if (wave == 0) {                           // 64 lanes = 64 experts
        float l = lg[lane];
        float sc = 1.0f / (1.0f + expf(-l));   // unbiased score (gate weight)
        float cur = sc + bias[lane];           // biased score (routing key)

        int i0, i1, i2, i3, i4, i5;
        float s0, s1, s2, s3, s4, s5;

#define ARGMAX_ROUND(IK, SK)                                                   \
        {                                                                      \
            float v = cur; int li = lane;                                      \
            _Pragma("unroll")                                                  \
            for (int o = 32; o; o >>= 1) {                                     \
                float ov = __shfl_down(v, o, 64);                              \
                int   oi = __shfl_down(li, o, 64);                             \
                if (ov > v || (ov == v && oi < li)) { v = ov; li = oi; }       \
            }                                                                  \
            li = __shfl(li, 0, 64);                                            \
            IK = li;                                                           \
            SK = __shfl(sc, li, 64);                                           \
            if (lane == li) cur = -1e30f;                                      \
        }
        ARGMAX_ROUND(i0, s0)
        ARGMAX_ROUND(i1, s1)
        ARGMAX_ROUND(i2, s2)
        ARGMAX_ROUND(i3, s3)
        ARGMAX_ROUND(i4, s4)
        ARGMAX_ROUND(i5, s5)
#undef ARGMAX_ROUND

        float inv = 1.0f / (s0 + s1 + s2 + s3 + s4 + s5 + 1e-20f);  // SCALE = 1.0
        if (lane == 0) {
            idx[0] = i0; idx[1] = i1; idx[2] = i2; idx[3] = i3; idx[4] = i4; idx[5] = i5;
            wgt[0] = s0 * inv; wgt[1] = s1 * inv; wgt[2] = s2 * inv;
            wgt[3] = s3 * inv; wgt[4] = s4 * inv; wgt[5] = s5 * inv;
        }
    }
}

// ---------------- Kernel 2: h[k][i] = silu(w1.x) * (w3.x) — 512-thr blocks ----------------
__global__ __launch_bounds__(512) void k_mlp1(const float* __restrict__ w1,
                                              const float* __restrict__ w3,
                                              const float* __restrict__ x,
                                              const int* __restrict__ idx,
                                              float* __restrict__ hbuf) {
    const int t = threadIdx.x;
    const int wave = t >> 6;
    const int lane = t & 63;
    const int g = blockIdx.x * 8 + wave;       // [0, TOP_K*INTER)
    const int k = g >> 10;                     // / INTER
    const int i = g & (INTER - 1);
    const int e = idx[k];                      // wave-uniform load, issues early

    const float4* x4 = (const float4*)x;
    float4 xr[8];
    #pragma unroll
    for (int j = 0; j < 8; j++) xr[j] = x4[lane + 64 * j];  // independent of idx

    const float4* a4 = (const float4*)(w1 + ((size_t)e * INTER + i) * HIDDEN);
    const float4* b4 = (const float4*)(w3 + ((size_t)e * INTER + i) * HIDDEN);
    float sg = 0.f, su = 0.f;
    #pragma unroll
    for (int j = 0; j < 8; j++) {
        float4 a = a4[lane + 64 * j];
        sg += a.x * xr[j].x + a.y * xr[j].y + a.z * xr[j].z + a.w * xr[j].w;
        float4 b = b4[lane + 64 * j];
        su += b.x * xr[j].x + b.y * xr[j].y + b.z * xr[j].z + b.w * xr[j].w;
    }
    #pragma unroll
    for (int o = 32; o; o >>= 1) {
        sg += __shfl_down(sg, o, 64);
        su += __shfl_down(su, o, 64);
    }
    if (lane == 0) {
        float gate = sg / (1.0f + expf(-sg));   // silu
        hbuf[k * INTER + i] = gate * su;
    }
}

// ---------------- Kernel 3: out[h] = sum_k w[k]*dot(w2[e_k][h], h_k) — 512-thr blocks ----------------
__global__ __launch_bounds__(512) void k_mlp2(const float* __restrict__ w2,
                                              const int* __restrict__ idx,
                                              const float* __restrict__ wgt,
                                              const float* __restrict__ hbuf,
                                              float* __restrict__ out) {
    const int t = threadIdx.x;
    const int wave = t >> 6;
    const int lane = t & 63;
    const int h = blockIdx.x * 8 + wave;       // [0, HIDDEN)
    const float4* h4 = (const float4*)hbuf;

    int e[TOP_K]; float w[TOP_K];
    #pragma unroll
    for (int k = 0; k < TOP_K; k++) { e[k] = idx[k]; w[k] = wgt[k]; }

    float acc = 0.f;
    #pragma unroll
    for (int k = 0; k < TOP_K; k++) {
        const float4* r4 = (const float4*)(w2 + ((size_t)e[k] * HIDDEN + h) * INTER);
        float s = 0.f;
        #pragma unroll
        for (int j = 0; j < 4; j++) {
            float4 a = r4[lane + 64 * j];
            float4 b = h4[k * (INTER / 4) + lane + 64 * j];
            s += a.x * b.x + a.y * b.y + a.z * b.z + a.w * b.w;
        }
        acc += w[k] * s;
    }
    #pragma unroll
    for (int o = 32; o; o >>= 1) acc += __shfl_down(acc, o, 64);
    if (lane == 0) out[h] = acc;
}

extern "C" void kernel_launch(void* const* d_in, const int* in_sizes, int n_in,
                              void* d_out, int out_size, void* d_ws, size_t ws_size,
                              hipStream_t stream) {
    const float* x    = (const float*)d_in[0];
    const float* gw   = (const float*)d_in[1];
    const float* bias = (const float*)d_in[2];
    const float* w1   = (const float*)d_in[3];
    const float* w2   = (const float*)d_in[4];
    const float* w3   = (const float*)d_in[5];
    float* out = (float*)d_out;

    float* ws_f    = (float*)d_ws;
    int*   idx     = (int*)(ws_f + 64);         // 6 ints
    float* wgt     = ws_f + 72;                 // 6 floats
    float* hbuf    = ws_f + 128;                // 6144 floats
    float* hbuf_d  = ws_f + 8192;               // dummy hbuf (measurement dup)
    float* out_d   = ws_f + 16384;              // dummy out  (measurement dup)

    // MEASUREMENT ROUND: mlp1/mlp2 dispatched twice; duplicates write to dummy
    // ws regions so the real dataflow and d_out are unchanged.
    // delta vs round-8 = M1_warm + M2_warm + 2*gap.
    k_route<<<1, 1024, 0, stream>>>(gw, x, bias, idx, wgt);
    k_mlp1<<<TOP_K * INTER / 8, 512, 0, stream>>>(w1, w3, x, idx, hbuf);
    k_mlp1<<<TOP_K * INTER / 8, 512, 0, stream>>>(w1, w3, x, idx, hbuf_d);
    k_mlp2<<<HIDDEN / 8, 512, 0, stream>>>(w2, idx, wgt, hbuf, out);
    k_mlp2<<<HIDDEN / 8, 512, 0, stream>>>(w2, idx, wgt, hbuf, out_d);
}

// Round 12
// 41.565 us; speedup vs baseline: 1.6069x; 1.6069x over previous
//
#include <hip/hip_runtime.h>
#include <math.h>

#define NUM_EXPERTS 64
#define TOP_K 6
#define HIDDEN 2048
#define INTER 1024

// ws layout (dwords): [0] ticket counter (memset to 0 each call)
//                     [64..69] idx, [72..77] wgt, [320..383] logits, [512..] hbuf

// ---------------- Kernel 1: gate GEMV (64 blocks) + last-block top-6 ----------------
__global__ __launch_bounds__(256) void k_gate_topk(const float* __restrict__ gw,
                                                   const float* __restrict__ x,
                                                   const float* __restrict__ bias,
                                                   unsigned* __restrict__ wsu,
                                                   int* __restrict__ idx,
                                                   float* __restrict__ wgt) {
    unsigned* counter = wsu;            // memset to 0 before this kernel each call
    unsigned* logits_u = wsu + 320;

    const int e = blockIdx.x;           // 64 blocks = 64 experts
    const int t = threadIdx.x;          // 256 threads
    const int wave = t >> 6;
    const int lane = t & 63;

    // logit_e = dot(gw[e], x) : 256 thr x 2 float4
    const float4* r4 = (const float4*)(gw + (size_t)e * HIDDEN);
    const float4* x4 = (const float4*)x;
    float sum = 0.f;
    #pragma unroll
    for (int i = t; i < HIDDEN / 4; i += 256) {
        float4 a = r4[i], b = x4[i];
        sum += a.x * b.x + a.y * b.y + a.z * b.z + a.w * b.w;
    }
    #pragma unroll
    for (int o = 32; o; o >>= 1) sum += __shfl_down(sum, o, 64);
    __shared__ float ls[4];
    if (lane == 0) ls[wave] = sum;
    __syncthreads();

    unsigned ticket = 0xFFFFFFFFu;
    if (t == 0) {
        float lg = ls[0] + ls[1] + ls[2] + ls[3];
        // release this block's logit, then take a ticket (ACQ_REL orders both)
        __hip_atomic_store(&logits_u[e], __float_as_uint(lg),
                           __ATOMIC_RELEASE, __HIP_MEMORY_SCOPE_AGENT);
        ticket = __hip_atomic_fetch_add(counter, 1u,
                                        __ATOMIC_ACQ_REL, __HIP_MEMORY_SCOPE_AGENT);
    }
    if (wave == 0) {
        bool last = (__shfl((int)ticket, 0, 64) == NUM_EXPERTS - 1);
        if (last) {
            // all 64 logit stores happened-before our ticket read (acq-rel chain)
            unsigned bits = __hip_atomic_load(&logits_u[lane],
                                              __ATOMIC_ACQUIRE, __HIP_MEMORY_SCOPE_AGENT);
            float sc = 1.0f / (1.0f + expf(-__uint_as_float(bits)));  // gate weight
            float cur = sc + bias[lane];                              // routing key

            int i0, i1, i2, i3, i4, i5;
            float s0, s1, s2, s3, s4, s5;
#define ARGMAX_ROUND(IK, SK)                                                   \
            {                                                                  \
                float v = cur; int li = lane;                                  \
                _Pragma("unroll")                                              \
                for (int o = 32; o; o >>= 1) {                                 \
                    float ov = __shfl_down(v, o, 64);                          \
                    int   oi = __shfl_down(li, o, 64);                         \
                    if (ov > v || (ov == v && oi < li)) { v = ov; li = oi; }   \
                }                                                              \
                li = __shfl(li, 0, 64);                                        \
                IK = li;                                                       \
                SK = __shfl(sc, li, 64);                                       \
                if (lane == li) cur = -1e30f;                                  \
            }
            ARGMAX_ROUND(i0, s0)
            ARGMAX_ROUND(i1, s1)
            ARGMAX_ROUND(i2, s2)
            ARGMAX_ROUND(i3, s3)
            ARGMAX_ROUND(i4, s4)
            ARGMAX_ROUND(i5, s5)
#undef ARGMAX_ROUND

            float inv = 1.0f / (s0 + s1 + s2 + s3 + s4 + s5 + 1e-20f);  // SCALE=1
            if (lane == 0) {
                idx[0] = i0; idx[1] = i1; idx[2] = i2;
                idx[3] = i3; idx[4] = i4; idx[5] = i5;
                wgt[0] = s0 * inv; wgt[1] = s1 * inv; wgt[2] = s2 * inv;
                wgt[3] = s3 * inv; wgt[4] = s4 * inv; wgt[5] = s5 * inv;
            }
        }
    }
}

// ---------------- Kernel 2: h[k][i] = silu(w1.x) * (w3.x) — 512-thr blocks ----------------
__global__ __launch_bounds__(512) void k_mlp1(const float* __restrict__ w1,
                                              const float* __restrict__ w3,
                                              const float* __restrict__ x,
                                              const int* __restrict__ idx,
                                              float* __restrict__ hbuf) {
    const int t = threadIdx.x;
    const int wave = t >> 6;
    const int lane = t & 63;
    const int g = blockIdx.x * 8 + wave;       // [0, TOP_K*INTER)
    const int k = g >> 10;                     // / INTER
    const int i = g & (INTER - 1);
    const int e = idx[k];                      // wave-uniform load, issues early

    const float4* x4 = (const float4*)x;
    float4 xr[8];
    #pragma unroll
    for (int j = 0; j < 8; j++) xr[j] = x4[lane + 64 * j];  // independent of idx

    const float4* a4 = (const float4*)(w1 + ((size_t)e * INTER + i) * HIDDEN);
    const float4* b4 = (const float4*)(w3 + ((size_t)e * INTER + i) * HIDDEN);
    float sg = 0.f, su = 0.f;
    #pragma unroll
    for (int j = 0; j < 8; j++) {
        float4 a = a4[lane + 64 * j];
        sg += a.x * xr[j].x + a.y * xr[j].y + a.z * xr[j].z + a.w * xr[j].w;
        float4 b = b4[lane + 64 * j];
        su += b.x * xr[j].x + b.y * xr[j].y + b.z * xr[j].z + b.w * xr[j].w;
    }
    #pragma unroll
    for (int o = 32; o; o >>= 1) {
        sg += __shfl_down(sg, o, 64);
        su += __shfl_down(su, o, 64);
    }
    if (lane == 0) {
        float gate = sg / (1.0f + expf(-sg));   // silu
        hbuf[k * INTER + i] = gate * su;
    }
}

// ---------------- Kernel 3: out[h] = sum_k w[k]*dot(w2[e_k][h], h_k) — 512-thr blocks ----------------
__global__ __launch_bounds__(512) void k_mlp2(const float* __restrict__ w2,
                                              const int* __restrict__ idx,
                                              const float* __restrict__ wgt,
                                              const float* __restrict__ hbuf,
                                              float* __restrict__ out) {
    const int t = threadIdx.x;
    const int wave = t >> 6;
    const int lane = t & 63;
    const int h = blockIdx.x * 8 + wave;       // [0, HIDDEN)
    const float4* h4 = (const float4*)hbuf;

    int e[TOP_K]; float w[TOP_K];
    #pragma unroll
    for (int k = 0; k < TOP_K; k++) { e[k] = idx[k]; w[k] = wgt[k]; }

    float acc = 0.f;
    #pragma unroll
    for (int k = 0; k < TOP_K; k++) {
        const float4* r4 = (const float4*)(w2 + ((size_t)e[k] * HIDDEN + h) * INTER);
        float s = 0.f;
        #pragma unroll
        for (int j = 0; j < 4; j++) {
            float4 a = r4[lane + 64 * j];
            float4 b = h4[k * (INTER / 4) + lane + 64 * j];
            s += a.x * b.x + a.y * b.y + a.z * b.z + a.w * b.w;
        }
        acc += w[k] * s;
    }
    #pragma unroll
    for (int o = 32; o; o >>= 1) acc += __shfl_down(acc, o, 64);
    if (lane == 0) out[h] = acc;
}

extern "C" void kernel_launch(void* const* d_in, const int* in_sizes, int n_in,
                              void* d_out, int out_size, void* d_ws, size_t ws_size,
                              hipStream_t stream) {
    const float* x    = (const float*)d_in[0];
    const float* gw   = (const float*)d_in[1];
    const float* bias = (const float*)d_in[2];
    const float* w1   = (const float*)d_in[3];
    const float* w2   = (const float*)d_in[4];
    const float* w3   = (const float*)d_in[5];
    float* out = (float*)d_out;

    unsigned* wsu  = (unsigned*)d_ws;
    float* ws_f    = (float*)d_ws;
    int*   idx     = (int*)(ws_f + 64);         // 6 ints
    float* wgt     = ws_f + 72;                 // 6 floats
    float* hbuf    = ws_f + 512;                // 6144 floats

    hipMemsetAsync(wsu, 0, 4, stream);          // zero ticket counter (graph node)
    k_gate_topk<<<NUM_EXPERTS, 256, 0, stream>>>(gw, x, bias, wsu, idx, wgt);
    k_mlp1<<<TOP_K * INTER / 8, 512, 0, stream>>>(w1, w3, x, idx, hbuf);
    k_mlp2<<<HIDDEN / 8, 512, 0, stream>>>(w2, idx, wgt, hbuf, out);
}

// Round 13
// 40.018 us; speedup vs baseline: 1.6690x; 1.0386x over previous
//
#include <hip/hip_runtime.h>
#include <math.h>

#define NUM_EXPERTS 64
#define TOP_K 6
#define HIDDEN 2048
#define INTER 1024

// ---------------- Kernel 1: routing — gate GEMV + top-6 in ONE block ----------------
// Champion structure (round 8): 1 block, 16 waves; wave 0 runs in-register top-6.
// Parallel-gate variants save ~3 µs of exec but re-add >=2 µs of sync/dispatch:
// measured wash or loss (rounds 2, 11, 12). Keep 1-block route.
__global__ __launch_bounds__(1024) void k_route(const float* __restrict__ gw,
                                                const float* __restrict__ x,
                                                const float* __restrict__ bias,
                                                int* __restrict__ idx,
                                                float* __restrict__ wgt) {
    __shared__ float4 xs[HIDDEN / 4];          // 8 KB
    __shared__ float  lg[NUM_EXPERTS];
    const int t = threadIdx.x;
    const int wave = t >> 6;
    const int lane = t & 63;

    const float4* x4 = (const float4*)x;
    if (t < HIDDEN / 4) xs[t] = x4[t];
    __syncthreads();

    float s[4] = {0.f, 0.f, 0.f, 0.f};
    #pragma unroll
    for (int q = 0; q < 4; q++) {
        const int e = wave * 4 + q;
        const float4* r4 = (const float4*)(gw + (size_t)e * HIDDEN);
        #pragma unroll
        for (int j = 0; j < 8; j++) {
            float4 a = r4[lane + 64 * j];
            float4 xv = xs[lane + 64 * j];
            s[q] += a.x * xv.x + a.y * xv.y + a.z * xv.z + a.w * xv.w;
        }
    }
    #pragma unroll
    for (int o = 32; o; o >>= 1) {
        #pragma unroll
        for (int q = 0; q < 4; q++) s[q] += __shfl_down(s[q], o, 64);
    }
    if (lane == 0) {
        #pragma unroll
        for (int q = 0; q < 4; q++) lg[wave * 4 + q] = s[q];
    }
    __syncthreads();

    if (wave == 0) {                           // 64 lanes = 64 experts
        float l = lg[lane];
        float sc = 1.0f / (1.0f + expf(-l));   // unbiased score (gate weight)
        float cur = sc + bias[lane];           // biased score (routing key)

        int i0, i1, i2, i3, i4, i5;
        float s0, s1, s2, s3, s4, s5;

#define ARGMAX_ROUND(IK, SK)                                                   \
        {                                                                      \
            float v = cur; int li = lane;                                      \
            _Pragma("unroll")                                                  \
            for (int o = 32; o; o >>= 1) {                                     \
                float ov = __shfl_down(v, o, 64);                              \
                int   oi = __shfl_down(li, o, 64);                             \
                if (ov > v || (ov == v && oi < li)) { v = ov; li = oi; }       \
            }                                                                  \
            li = __shfl(li, 0, 64);                                            \
            IK = li;                                                           \
            SK = __shfl(sc, li, 64);                                           \
            if (lane == li) cur = -1e30f;                                      \
        }
        ARGMAX_ROUND(i0, s0)
        ARGMAX_ROUND(i1, s1)
        ARGMAX_ROUND(i2, s2)
        ARGMAX_ROUND(i3, s3)
        ARGMAX_ROUND(i4, s4)
        ARGMAX_ROUND(i5, s5)
#undef ARGMAX_ROUND

        float inv = 1.0f / (s0 + s1 + s2 + s3 + s4 + s5 + 1e-20f);  // SCALE = 1.0
        if (lane == 0) {
            idx[0] = i0; idx[1] = i1; idx[2] = i2; idx[3] = i3; idx[4] = i4; idx[5] = i5;
            wgt[0] = s0 * inv; wgt[1] = s1 * inv; wgt[2] = s2 * inv;
            wgt[3] = s3 * inv; wgt[4] = s4 * inv; wgt[5] = s5 * inv;
        }
    }
}

// ---------------- Kernel 2: h[k][i] = silu(w1.x) * (w3.x) — 512-thr blocks ----------------
// At HBM floor (round-11 measurement): 96 MB stream, one wave per inter-row.
__global__ __launch_bounds__(512) void k_mlp1(const float* __restrict__ w1,
                                              const float* __restrict__ w3,
                                              const float* __restrict__ x,
                                              const int* __restrict__ idx,
                                              float* __restrict__ hbuf) {
    const int t = threadIdx.x;
    const int wave = t >> 6;
    const int lane = t & 63;
    const int g = blockIdx.x * 8 + wave;       // [0, TOP_K*INTER)
    const int k = g >> 10;                     // / INTER
    const int i = g & (INTER - 1);
    const int e = idx[k];                      // wave-uniform load, issues early

    const float4* x4 = (const float4*)x;
    float4 xr[8];
    #pragma unroll
    for (int j = 0; j < 8; j++) xr[j] = x4[lane + 64 * j];  // independent of idx

    const float4* a4 = (const float4*)(w1 + ((size_t)e * INTER + i) * HIDDEN);
    const float4* b4 = (const float4*)(w3 + ((size_t)e * INTER + i) * HIDDEN);
    float sg = 0.f, su = 0.f;
    #pragma unroll
    for (int j = 0; j < 8; j++) {
        float4 a = a4[lane + 64 * j];
        sg += a.x * xr[j].x + a.y * xr[j].y + a.z * xr[j].z + a.w * xr[j].w;
        float4 b = b4[lane + 64 * j];
        su += b.x * xr[j].x + b.y * xr[j].y + b.z * xr[j].z + b.w * xr[j].w;
    }
    #pragma unroll
    for (int o = 32; o; o >>= 1) {
        sg += __shfl_down(sg, o, 64);
        su += __shfl_down(su, o, 64);
    }
    if (lane == 0) {
        float gate = sg / (1.0f + expf(-sg));   // silu
        hbuf[k * INTER + i] = gate * su;
    }
}

// ---------------- Kernel 3: out[h] = sum_k w[k]*dot(w2[e_k][h], h_k) — 512-thr blocks ----------------
// At HBM floor: 48 MB stream; routing data hoisted into registers up front.
__global__ __launch_bounds__(512) void k_mlp2(const float* __restrict__ w2,
                                              const int* __restrict__ idx,
                                              const float* __restrict__ wgt,
                                              const float* __restrict__ hbuf,
                                              float* __restrict__ out) {
    const int t = threadIdx.x;
    const int wave = t >> 6;
    const int lane = t & 63;
    const int h = blockIdx.x * 8 + wave;       // [0, HIDDEN)
    const float4* h4 = (const float4*)hbuf;

    int e[TOP_K]; float w[TOP_K];
    #pragma unroll
    for (int k = 0; k < TOP_K; k++) { e[k] = idx[k]; w[k] = wgt[k]; }

    float acc = 0.f;
    #pragma unroll
    for (int k = 0; k < TOP_K; k++) {
        const float4* r4 = (const float4*)(w2 + ((size_t)e[k] * HIDDEN + h) * INTER);
        float s = 0.f;
        #pragma unroll
        for (int j = 0; j < 4; j++) {
            float4 a = r4[lane + 64 * j];
            float4 b = h4[k * (INTER / 4) + lane + 64 * j];
            s += a.x * b.x + a.y * b.y + a.z * b.z + a.w * b.w;
        }
        acc += w[k] * s;
    }
    #pragma unroll
    for (int o = 32; o; o >>= 1) acc += __shfl_down(acc, o, 64);
    if (lane == 0) out[h] = acc;
}

extern "C" void kernel_launch(void* const* d_in, const int* in_sizes, int n_in,
                              void* d_out, int out_size, void* d_ws, size_t ws_size,
                              hipStream_t stream) {
    const float* x    = (const float*)d_in[0];
    const float* gw   = (const float*)d_in[1];
    const float* bias = (const float*)d_in[2];
    const float* w1   = (const float*)d_in[3];
    const float* w2   = (const float*)d_in[4];
    const float* w3   = (const float*)d_in[5];
    float* out = (float*)d_out;

    float* ws_f   = (float*)d_ws;
    int*   idx    = (int*)(ws_f + 64);          // 6 ints
    float* wgt    = ws_f + 72;                  // 6 floats
    float* hbuf   = ws_f + 128;                 // TOP_K*INTER = 6144 floats

    k_route<<<1, 1024, 0, stream>>>(gw, x, bias, idx, wgt);
    k_mlp1<<<TOP_K * INTER / 8, 512, 0, stream>>>(w1, w3, x, idx, hbuf);
    k_mlp2<<<HIDDEN / 8, 512, 0, stream>>>(w2, idx, wgt, hbuf, out);
}